// Round 22
// baseline (326.674 us; speedup 1.0000x reference)
//
#include <hip/hip_runtime.h>
#include <hip/hip_cooperative_groups.h>

namespace cg = cooperative_groups;

typedef unsigned short u16;
typedef unsigned char u8;
typedef __attribute__((ext_vector_type(8))) short bf16x8;
typedef __attribute__((ext_vector_type(4))) float f32x4;
typedef __attribute__((ext_vector_type(2))) float f32x2;

#define ICNST 128
#define C2 256   // OC*WIDTH (bf16 channels; fp8 row = 256 B)

__device__ __forceinline__ float bf2f(u16 u){
  return __uint_as_float(((unsigned int)u) << 16);
}
__device__ __forceinline__ u16 f2bf(float f){
  unsigned int u = __float_as_uint(f);
  unsigned int r = (u + 0x7fffu + ((u >> 16) & 1u)) >> 16;
  return (u16)r;
}
__device__ __forceinline__ unsigned int pk2(float a, float b){
  return (unsigned int)f2bf(a) | ((unsigned int)f2bf(b) << 16);
}

// ---- fp8 e4m3 helpers (HW cvt on gfx950; manual fallback) ----
#if defined(__has_builtin)
#if __has_builtin(__builtin_amdgcn_cvt_pk_f32_fp8) && __has_builtin(__builtin_amdgcn_cvt_pk_fp8_f32)
#define HAVE_FP8_BUILTINS 1
#endif
#endif

#ifndef HAVE_FP8_BUILTINS
__device__ __forceinline__ float fp8tof(unsigned int b){
  unsigned int sgn = (b & 0x80u) << 24;
  unsigned int em = b & 0x7fu;
  float mag;
  if (em >= 8u){
    unsigned int e = em >> 3, m = em & 7u;
    mag = __uint_as_float(((e + 120u) << 23) | (m << 20));
  } else {
    mag = (float)em * 0.001953125f; // 2^-9
  }
  return __uint_as_float(__float_as_uint(mag) | sgn);
}
__device__ __forceinline__ unsigned int ftofp8(float f){
  unsigned int u = __float_as_uint(f);
  unsigned int s = (u >> 24) & 0x80u;
  float a = __uint_as_float(u & 0x7fffffffu);
  if (a > 448.f) a = 448.f;
  if (a < 0.015625f){
    int q = (int)(a * 512.f + 0.5f);
    return s | (unsigned int)q;
  }
  int e; float m = frexpf(a, &e);
  int q = (int)(m * 16.f + 0.5f);
  if (q == 16){ q = 8; e += 1; }
  int E = e - 1 + 7;
  if (E > 15){ E = 15; q = 14; }
  return s | (unsigned int)((E << 3) | (q & 7));
}
#endif

template<bool HI>
__device__ __forceinline__ f32x2 up2(unsigned int v){
#ifdef HAVE_FP8_BUILTINS
  return __builtin_amdgcn_cvt_pk_f32_fp8(v, HI);
#else
  f32x2 r;
  constexpr unsigned int sh = HI ? 16u : 0u;
  r.x = fp8tof((v >> sh) & 0xffu);
  r.y = fp8tof((v >> (sh + 8u)) & 0xffu);
  return r;
#endif
}
__device__ __forceinline__ unsigned int pk4fp8(float a, float b, float c, float d){
#ifdef HAVE_FP8_BUILTINS
  unsigned int o = (unsigned int)__builtin_amdgcn_cvt_pk_fp8_f32(a, b, 0, false);
  o = (unsigned int)__builtin_amdgcn_cvt_pk_fp8_f32(c, d, (int)o, true);
  return o;
#else
  return ftofp8(a) | (ftofp8(b) << 8) | (ftofp8(c) << 16) | (ftofp8(d) << 24);
#endif
}

// ---- ONE cooperative preprocessing kernel: zero + cvt + deg + scan + scatter ----
// 256 blocks x 256 threads (1 block/CU, co-resident). Requires n <= 65536.
__global__ void k_prep(const int* __restrict__ srcp, const int* __restrict__ dstp,
    int* __restrict__ deg, const float* __restrict__ Wpre,
    const float* __restrict__ Wmrg, const float* __restrict__ Wcv,
    u16* __restrict__ WT, u16* __restrict__ Wc,
    int* __restrict__ row_start, int* __restrict__ cursor,
    float* __restrict__ norm, int* __restrict__ bsum,
    int* __restrict__ csr, int n, int E){
  cg::grid_group grid = cg::this_grid();
  __shared__ int s[256];
  __shared__ int s2[256];
  int t = threadIdx.x, b = blockIdx.x;
  int gid = b * 256 + t;
  const int gsz = 256 * 256;

  // phase 0: zero deg
  for (int i = gid; i < n; i += gsz) deg[i] = 0;
  grid.sync();

  // phase 1: weight conversion + degree count
  {
    int i = gid;               // 65536 threads, 65536 elements: exactly one each
    int j = i & 511, k = i >> 9;
    float v = (j < 256) ? Wpre[k * 256 + j] : Wmrg[k * 256 + (j - 256)];
    WT[j * 128 + k] = f2bf(v);
  }
  if (gid < 32768) Wc[gid] = f2bf(Wcv[gid]);
  for (int e = gid; e < E; e += gsz) atomicAdd(&deg[dstp[e]], 1);
  grid.sync();

  // phase 2: block-local inclusive scan of this block's chunk (C <= 256)
  int C = (n + 255) >> 8;
  int base = b * C;
  int v = 0;
  if (t < C && base + t < n) v = deg[base + t];
  s[t] = v;
  __syncthreads();
  for (int off = 1; off < 256; off <<= 1){
    int u = (t >= off) ? s[t - off] : 0;
    __syncthreads();
    s[t] += u;
    __syncthreads();
  }
  if (t == 255) bsum[b] = s[255];
  grid.sync();

  // phase 3: block 0 exclusive-scans the 256 block sums
  if (b == 0){
    int v2 = bsum[t];
    s2[t] = v2;
    __syncthreads();
    for (int off = 1; off < 256; off <<= 1){
      int u = (t >= off) ? s2[t - off] : 0;
      __syncthreads();
      s2[t] += u;
      __syncthreads();
    }
    bsum[t] = s2[t] - v2;
  }
  grid.sync();

  // phase 4: finalize row_start / cursor / norm
  {
    int i = base + t;
    int ex = s[t] - v + bsum[b];
    if (t < C && i < n){
      row_start[i] = ex;
      cursor[i] = ex;
      norm[i] = (v > 0) ? rsqrtf((float)v) : 0.f;
      if (i == n - 1) row_start[n] = ex + v;
    }
  }
  grid.sync();

  // phase 5: scatter edges into CSR slots
  for (int e = gid; e < E; e += gsz){
    int d = dstp[e];
    int pos = atomicAdd(&cursor[d], 1);
    csr[pos] = srcp[e];
  }
}

// ---- init (MFMA, swapped-D): merge = X@Wm + bm (bf16); outA = fp8(norm.*relu(X@Wp+bp+merge))
__global__ __launch_bounds__(512) void k_initM(const float* __restrict__ node,
    const u16* __restrict__ WT, const float* __restrict__ bpre,
    const float* __restrict__ bmrg, const float* __restrict__ norm,
    u16* __restrict__ merge, u8* __restrict__ outA, int n){
  __shared__ u16 Al[64 * 128];  // A tile, swizzled, 16KB
  int t = threadIdx.x;
  int w = t >> 6, l = t & 63;
  int n0 = blockIdx.x * 64;
  int cb = w * 32;
  int lk = (l >> 4) * 8;

  float nr4[4];
  #pragma unroll
  for (int fr = 0; fr < 4; ++fr){
    int row = n0 + fr * 16 + (l & 15);
    nr4[fr] = (row < n) ? norm[row] : 0.f;
  }
  float4 bPr[2], bMr[2];
  #pragma unroll
  for (int fcp = 0; fcp < 2; ++fcp){
    int j0 = cb + fcp * 16 + (l >> 4) * 4;
    bPr[fcp] = *(const float4*)(bpre + j0);
    bMr[fcp] = *(const float4*)(bmrg + j0);
  }

  {
    int row = t >> 3, c0 = (t & 7) * 16;
    const float* src = node + (size_t)(n0 + row) * ICNST + c0;
    bool ok = (n0 + row) < n;
    #pragma unroll
    for (int q = 0; q < 4; ++q){
      float4 v = ok ? *(const float4*)(src + q * 4) : float4{0.f, 0.f, 0.f, 0.f};
      int byte = (row * 256 + c0 * 2 + q * 8) ^ ((row & 7) << 4);
      uint2 pp; pp.x = pk2(v.x, v.y); pp.y = pk2(v.z, v.w);
      *(uint2*)((char*)Al + byte) = pp;
    }
  }
  __syncthreads();

  f32x4 acc[4][4] = {};
  #pragma unroll
  for (int ks = 0; ks < 4; ++ks){
    bf16x8 bf[4];
    #pragma unroll
    for (int fc = 0; fc < 4; ++fc){
      int j = (fc < 2) ? (cb + fc * 16 + (l & 15))
                       : (256 + cb + (fc - 2) * 16 + (l & 15));
      bf[fc] = *(const bf16x8*)(WT + (size_t)j * 128 + ks * 32 + lk);
    }
    bf16x8 af[4];
    #pragma unroll
    for (int fr = 0; fr < 4; ++fr){
      int row = fr * 16 + (l & 15);
      int byte = (row * 256 + ks * 64 + (l >> 4) * 16) ^ ((l & 7) << 4);
      af[fr] = *(const bf16x8*)((const char*)Al + byte);
    }
    #pragma unroll
    for (int fr = 0; fr < 4; ++fr)
      #pragma unroll
      for (int fc = 0; fc < 4; ++fc)
        acc[fr][fc] = __builtin_amdgcn_mfma_f32_16x16x32_bf16(bf[fc], af[fr], acc[fr][fc], 0, 0, 0);
  }

  #pragma unroll
  for (int fr = 0; fr < 4; ++fr){
    int row = n0 + fr * 16 + (l & 15);
    bool ok = row < n;
    float nr = nr4[fr];
    #pragma unroll
    for (int fcp = 0; fcp < 2; ++fcp){
      int j0 = cb + fcp * 16 + (l >> 4) * 4;
      f32x4 aP = acc[fr][fcp], aM = acc[fr][fcp + 2];
      float bPe[4] = {bPr[fcp].x, bPr[fcp].y, bPr[fcp].z, bPr[fcp].w};
      float bMe[4] = {bMr[fcp].x, bMr[fcp].y, bMr[fcp].z, bMr[fcp].w};
      ushort4 mgv;
      u16* mgp = (u16*)&mgv;
      float o4[4];
      #pragma unroll
      for (int r = 0; r < 4; ++r){
        float mg = aM[r] + bMe[r];
        float o  = aP[r] + bPe[r] + mg;
        o = (o > 0.f) ? o : 0.f;
        mgp[r] = f2bf(mg);
        o4[r] = nr * o;
      }
      if (ok){
        *(ushort4*)(merge + (size_t)row * C2 + j0) = mgv;
        *(unsigned int*)(outA + (size_t)row * C2 + j0) = pk4fp8(o4[0], o4[1], o4[2], o4[3]);
      }
    }
  }
}

// ---- FUSED prop + conv (MFMA, swapped-D), fp8 state ----
// PROP: quarter-wave (16 lanes x uint4 = one 256B row per quarter)
template<int FINAL>
__global__ __launch_bounds__(512) void k_pconv(const u8* __restrict__ src,
    const int* __restrict__ row_start, const int* __restrict__ csr,
    const float* __restrict__ norm,
    const u16* __restrict__ Wc, const float* __restrict__ bc,
    const u16* __restrict__ merge,
    u8* __restrict__ dstB, float* __restrict__ out, int n, int Etot){
  __shared__ u16 Al[64 * 256];  // bf16 A tile (prop result), swizzled, 32KB
  int t = threadIdx.x;
  int w = t >> 6, l = t & 63;
  int n0 = blockIdx.x * 64;
  int wh = w >> 2;
  int lk = (l >> 4) * 8;
  int q = l >> 4;               // quarter index 0..3
  int c16 = l & 15;             // lane-in-quarter: 16B (16 fp8 channels) per lane

  float nr4[4];
  #pragma unroll
  for (int fr = 0; fr < 4; ++fr){
    int row = n0 + fr * 16 + (l & 15);
    nr4[fr] = (row < n) ? norm[row] : 0.f;
  }
  float4 bCr[2];
  #pragma unroll
  for (int fc = 0; fc < 2; ++fc)
    bCr[fc] = *(const float4*)(bc + w * 32 + fc * 16 + (l >> 4) * 4);

  // ---- PROP phase: quarter-wave owns 2 rows in flight; uint4 row segments ----
  const u8* Ac = src + (size_t)c16 * 16;
  int rbase = w * 8 + q * 2;
  float acc16[2][16];
  int bb[2], ee[2];
  float ndk[2];
  #pragma unroll
  for (int k = 0; k < 2; ++k){
    int gw = n0 + rbase + k;
    bool ok = gw < n;
    bb[k] = ok ? row_start[gw] : 0;
    ee[k] = ok ? row_start[gw + 1] : 0;
    ndk[k] = ok ? norm[gw] : 0.f;
    #pragma unroll
    for (int m = 0; m < 16; ++m) acc16[k][m] = 0.f;
  }
  int Em1 = Etot - 1;
  bool more = (bb[0] < ee[0]) | (bb[1] < ee[1]);
  while (__any(more)){
    uint4 rr[2];
    float wk[2];
    #pragma unroll
    for (int k = 0; k < 2; ++k){
      bool v = bb[k] < ee[k];
      wk[k] = v ? 1.f : 0.f;
      int idx = (bb[k] < Em1) ? bb[k] : Em1;
      int s0 = csr[idx];
      rr[k] = *(const uint4*)(Ac + (size_t)s0 * C2);
      bb[k] += v ? 1 : 0;
    }
    #pragma unroll
    for (int k = 0; k < 2; ++k){
      f32x2 p;
      p = up2<false>(rr[k].x); acc16[k][ 0] = fmaf(wk[k], p.x, acc16[k][ 0]); acc16[k][ 1] = fmaf(wk[k], p.y, acc16[k][ 1]);
      p = up2<true >(rr[k].x); acc16[k][ 2] = fmaf(wk[k], p.x, acc16[k][ 2]); acc16[k][ 3] = fmaf(wk[k], p.y, acc16[k][ 3]);
      p = up2<false>(rr[k].y); acc16[k][ 4] = fmaf(wk[k], p.x, acc16[k][ 4]); acc16[k][ 5] = fmaf(wk[k], p.y, acc16[k][ 5]);
      p = up2<true >(rr[k].y); acc16[k][ 6] = fmaf(wk[k], p.x, acc16[k][ 6]); acc16[k][ 7] = fmaf(wk[k], p.y, acc16[k][ 7]);
      p = up2<false>(rr[k].z); acc16[k][ 8] = fmaf(wk[k], p.x, acc16[k][ 8]); acc16[k][ 9] = fmaf(wk[k], p.y, acc16[k][ 9]);
      p = up2<true >(rr[k].z); acc16[k][10] = fmaf(wk[k], p.x, acc16[k][10]); acc16[k][11] = fmaf(wk[k], p.y, acc16[k][11]);
      p = up2<false>(rr[k].w); acc16[k][12] = fmaf(wk[k], p.x, acc16[k][12]); acc16[k][13] = fmaf(wk[k], p.y, acc16[k][13]);
      p = up2<true >(rr[k].w); acc16[k][14] = fmaf(wk[k], p.x, acc16[k][14]); acc16[k][15] = fmaf(wk[k], p.y, acc16[k][15]);
    }
    more = (bb[0] < ee[0]) | (bb[1] < ee[1]);
  }
  // write 2 rows (16 bf16 channels per lane = 32B = 2x uint4) to swizzled LDS
  #pragma unroll
  for (int k = 0; k < 2; ++k){
    int rl = rbase + k;
    float nd = ndk[k];
    uint4 v0, v1;
    v0.x = pk2(nd * acc16[k][ 0], nd * acc16[k][ 1]);
    v0.y = pk2(nd * acc16[k][ 2], nd * acc16[k][ 3]);
    v0.z = pk2(nd * acc16[k][ 4], nd * acc16[k][ 5]);
    v0.w = pk2(nd * acc16[k][ 6], nd * acc16[k][ 7]);
    v1.x = pk2(nd * acc16[k][ 8], nd * acc16[k][ 9]);
    v1.y = pk2(nd * acc16[k][10], nd * acc16[k][11]);
    v1.z = pk2(nd * acc16[k][12], nd * acc16[k][13]);
    v1.w = pk2(nd * acc16[k][14], nd * acc16[k][15]);
    int base2 = rl * 512 + c16 * 32;
    int sw = (rl & 7) << 4;
    *(uint4*)((char*)Al + (base2 ^ sw)) = v0;
    *(uint4*)((char*)Al + ((base2 + 16) ^ sw)) = v1;
  }
  __syncthreads();

  // ---- CONV phase ----
  f32x4 acc[4][2] = {};
  #pragma unroll
  for (int ks = 0; ks < 4; ++ks){
    bf16x8 bf[2];
    #pragma unroll
    for (int fc = 0; fc < 2; ++fc){
      int rw = w * 32 + fc * 16 + (l & 15);
      bf[fc] = *(const bf16x8*)(Wc + (size_t)rw * 128 + ks * 32 + lk);
    }
    bf16x8 af[4];
    #pragma unroll
    for (int fr = 0; fr < 4; ++fr){
      int row = fr * 16 + (l & 15);
      int byte = (row * 512 + wh * 256 + ks * 64 + (l >> 4) * 16) ^ ((l & 7) << 4);
      af[fr] = *(const bf16x8*)((const char*)Al + byte);
    }
    #pragma unroll
    for (int fr = 0; fr < 4; ++fr)
      #pragma unroll
      for (int fc = 0; fc < 2; ++fc)
        acc[fr][fc] = __builtin_amdgcn_mfma_f32_16x16x32_bf16(bf[fc], af[fr], acc[fr][fc], 0, 0, 0);
  }

  // epilogue
  #pragma unroll
  for (int fr = 0; fr < 4; ++fr){
    int row = n0 + fr * 16 + (l & 15);
    bool ok = row < n;
    float nr = nr4[fr];
    #pragma unroll
    for (int fc = 0; fc < 2; ++fc){
      int j0 = w * 32 + fc * 16 + (l >> 4) * 4;
      ushort4 mg4 = ok ? *(const ushort4*)(merge + (size_t)row * C2 + j0)
                       : ushort4{0, 0, 0, 0};
      const u16* mge = (const u16*)&mg4;
      float bCe[4] = {bCr[fc].x, bCr[fc].y, bCr[fc].z, bCr[fc].w};
      float v[4];
      #pragma unroll
      for (int r = 0; r < 4; ++r){
        float o = acc[fr][fc][r] + bCe[r] + bf2f(mge[r]);
        v[r] = (o > 0.f) ? o : 0.f;
      }
      if (ok){
        if (!FINAL){
          *(unsigned int*)(dstB + (size_t)row * C2 + j0) =
              pk4fp8(nr * v[0], nr * v[1], nr * v[2], nr * v[3]);
        } else {
          float2 om;
          om.x = 0.5f * (v[0] + v[1]);
          om.y = 0.5f * (v[2] + v[3]);
          *(float2*)(out + (size_t)row * 128 + (j0 >> 1)) = om;
        }
      }
    }
  }
}

extern "C" void kernel_launch(void* const* d_in, const int* in_sizes, int n_in,
                              void* d_out, int out_size, void* d_ws, size_t ws_size,
                              hipStream_t stream){
  const float* node = (const float*)d_in[0];
  const int*   eidx = (const int*)d_in[1];
  const float* Wpre = (const float*)d_in[2];
  const float* bpre = (const float*)d_in[3];
  const float* Wmrg = (const float*)d_in[4];
  const float* bmrg = (const float*)d_in[5];
  const float* Wcv  = (const float*)d_in[6];
  const float* bcv  = (const float*)d_in[7];
  float* out = (float*)d_out;

  const int n = in_sizes[0] / ICNST;
  const int E = in_sizes[1] / 2;
  const int* srcp = eidx;
  const int* dstp = eidx + E;

  char* ws = (char*)d_ws;
  size_t off = 0;
  auto alloc = [&](size_t bytes) -> char* {
    char* p = ws + off;
    off += bytes;
    off = (off + 255) & ~(size_t)255;
    return p;
  };
  int*   deg       = (int*)  alloc((size_t)n * 4);
  float* norm      = (float*)alloc((size_t)n * 4);
  int*   row_start = (int*)  alloc((size_t)(n + 1) * 4);
  int*   cursor    = (int*)  alloc((size_t)n * 4);
  int*   csr       = (int*)  alloc((size_t)E * 4);
  u16*   merge     = (u16*)  alloc((size_t)n * C2 * 2);
  u8*    bufA      = (u8*)   alloc((size_t)n * C2);
  u8*    bufB      = (u8*)   alloc((size_t)n * C2);
  u16*   WT        = (u16*)  alloc((size_t)512 * 128 * 2);
  u16*   Wcbf      = (u16*)  alloc((size_t)2 * 128 * 128 * 2);
  int*   bsum      = (int*)  alloc((size_t)256 * 4);
  (void)ws_size; (void)n_in; (void)out_size;

  // ---- single cooperative preprocessing kernel ----
  {
    void* args[] = {
      (void*)&srcp, (void*)&dstp, (void*)&deg, (void*)&Wpre, (void*)&Wmrg,
      (void*)&Wcv, (void*)&WT, (void*)&Wcbf, (void*)&row_start, (void*)&cursor,
      (void*)&norm, (void*)&bsum, (void*)&csr, (void*)&n, (void*)&E
    };
    hipLaunchCooperativeKernel((void*)k_prep, dim3(256), dim3(256), args, 0, stream);
  }

  int gb64 = (n + 63) / 64;
  k_initM<<<gb64, 512, 0, stream>>>(node, WT, bpre, bmrg, norm, merge, bufA, n);

  // iteration 1: fused prop+conv, bufA(fp8) -> bufB(fp8)
  k_pconv<0><<<gb64, 512, 0, stream>>>(bufA, row_start, csr, norm, Wcbf, bcv, merge, bufB, nullptr, n, E);
  // iteration 2: fused prop+conv + final mean, bufB(fp8) -> out (f32)
  k_pconv<1><<<gb64, 512, 0, stream>>>(bufB, row_start, csr, norm, Wcbf, bcv, merge, nullptr, out, n, E);
}

// Round 23
// 192.219 us; speedup vs baseline: 1.6995x; 1.6995x over previous
//
#include <hip/hip_runtime.h>

typedef unsigned short u16;
typedef unsigned char u8;
typedef __attribute__((ext_vector_type(8))) short bf16x8;
typedef __attribute__((ext_vector_type(4))) float f32x4;
typedef __attribute__((ext_vector_type(2))) float f32x2;

#define ICNST 128
#define C2 256   // OC*WIDTH (bf16 channels; fp8 row = 256 B)

__device__ __forceinline__ float bf2f(u16 u){
  return __uint_as_float(((unsigned int)u) << 16);
}
__device__ __forceinline__ u16 f2bf(float f){
  unsigned int u = __float_as_uint(f);
  unsigned int r = (u + 0x7fffu + ((u >> 16) & 1u)) >> 16;
  return (u16)r;
}
__device__ __forceinline__ unsigned int pk2(float a, float b){
  return (unsigned int)f2bf(a) | ((unsigned int)f2bf(b) << 16);
}

// ---- fp8 e4m3 helpers (HW cvt on gfx950; manual fallback) ----
#if defined(__has_builtin)
#if __has_builtin(__builtin_amdgcn_cvt_pk_f32_fp8) && __has_builtin(__builtin_amdgcn_cvt_pk_fp8_f32)
#define HAVE_FP8_BUILTINS 1
#endif
#endif

#ifndef HAVE_FP8_BUILTINS
__device__ __forceinline__ float fp8tof(unsigned int b){
  unsigned int sgn = (b & 0x80u) << 24;
  unsigned int em = b & 0x7fu;
  float mag;
  if (em >= 8u){
    unsigned int e = em >> 3, m = em & 7u;
    mag = __uint_as_float(((e + 120u) << 23) | (m << 20));
  } else {
    mag = (float)em * 0.001953125f; // 2^-9
  }
  return __uint_as_float(__float_as_uint(mag) | sgn);
}
__device__ __forceinline__ unsigned int ftofp8(float f){
  unsigned int u = __float_as_uint(f);
  unsigned int s = (u >> 24) & 0x80u;
  float a = __uint_as_float(u & 0x7fffffffu);
  if (a > 448.f) a = 448.f;
  if (a < 0.015625f){
    int q = (int)(a * 512.f + 0.5f);
    return s | (unsigned int)q;
  }
  int e; float m = frexpf(a, &e);
  int q = (int)(m * 16.f + 0.5f);
  if (q == 16){ q = 8; e += 1; }
  int E = e - 1 + 7;
  if (E > 15){ E = 15; q = 14; }
  return s | (unsigned int)((E << 3) | (q & 7));
}
#endif

template<bool HI>
__device__ __forceinline__ f32x2 up2(unsigned int v){
#ifdef HAVE_FP8_BUILTINS
  return __builtin_amdgcn_cvt_pk_f32_fp8(v, HI);
#else
  f32x2 r;
  constexpr unsigned int sh = HI ? 16u : 0u;
  r.x = fp8tof((v >> sh) & 0xffu);
  r.y = fp8tof((v >> (sh + 8u)) & 0xffu);
  return r;
#endif
}
__device__ __forceinline__ unsigned int pk4fp8(float a, float b, float c, float d){
#ifdef HAVE_FP8_BUILTINS
  unsigned int o = (unsigned int)__builtin_amdgcn_cvt_pk_fp8_f32(a, b, 0, false);
  o = (unsigned int)__builtin_amdgcn_cvt_pk_fp8_f32(c, d, (int)o, true);
  return o;
#else
  return ftofp8(a) | (ftofp8(b) << 8) | (ftofp8(c) << 16) | (ftofp8(d) << 24);
#endif
}

// ---- zero deg ----
__global__ __launch_bounds__(512) void k_zero(int* __restrict__ deg, int n){
  int i = blockIdx.x * 512 + threadIdx.x;
  if (i < n) deg[i] = 0;
}

// ---- fused: weight bf16 conversion (blocks 0..383) + degree count ----
__global__ __launch_bounds__(256) void k_pre(const int* __restrict__ dst,
    int* __restrict__ deg, const float* __restrict__ Wpre,
    const float* __restrict__ Wmrg, const float* __restrict__ Wcv,
    u16* __restrict__ WT, u16* __restrict__ Wc, int E){
  int bid = blockIdx.x;
  if (bid < 384){
    int idx = bid * 256 + threadIdx.x;
    if (idx < 65536){
      int j = idx & 511, k = idx >> 9;
      float v = (j < 256) ? Wpre[k * 256 + j] : Wmrg[k * 256 + (j - 256)];
      WT[j * 128 + k] = f2bf(v);
    } else if (idx < 65536 + 32768){
      int x = idx - 65536;
      Wc[x] = f2bf(Wcv[x]);
    }
  } else {
    int e = (bid - 384) * 256 + threadIdx.x;
    if (e < E) atomicAdd(&deg[dst[e]], 1);
  }
}

// ---- hierarchical scan ----
__global__ __launch_bounds__(256) void k_scan1(const int* __restrict__ deg,
    int* __restrict__ bsum, int n){
  __shared__ int red[256];
  int t = threadIdx.x;
  int i = blockIdx.x * 256 + t;
  red[t] = (i < n) ? deg[i] : 0;
  __syncthreads();
  for (int off = 128; off > 0; off >>= 1){
    if (t < off) red[t] += red[t + off];
    __syncthreads();
  }
  if (t == 0) bsum[blockIdx.x] = red[0];
}

__global__ __launch_bounds__(256) void k_scan2(int* __restrict__ bsum, int nb){
  __shared__ int s[256];
  int t = threadIdx.x;
  int v = (t < nb) ? bsum[t] : 0;
  s[t] = v;
  __syncthreads();
  for (int off = 1; off < 256; off <<= 1){
    int u = (t >= off) ? s[t - off] : 0;
    __syncthreads();
    s[t] += u;
    __syncthreads();
  }
  if (t < nb) bsum[t] = s[t] - v;
}

__global__ __launch_bounds__(256) void k_scan3(const int* __restrict__ deg,
    const int* __restrict__ bsum, int* __restrict__ row_start,
    int* __restrict__ cursor, float* __restrict__ norm, int n){
  __shared__ int s[256];
  int t = threadIdx.x;
  int i = blockIdx.x * 256 + t;
  int v = (i < n) ? deg[i] : 0;
  s[t] = v;
  __syncthreads();
  for (int off = 1; off < 256; off <<= 1){
    int u = (t >= off) ? s[t - off] : 0;
    __syncthreads();
    s[t] += u;
    __syncthreads();
  }
  int ex = s[t] - v + bsum[blockIdx.x];
  if (i < n){
    row_start[i] = ex;
    cursor[i] = ex;
    norm[i] = (v > 0) ? rsqrtf((float)v) : 0.f;
    if (i == n - 1) row_start[n] = ex + v;
  }
}

__global__ void k_scatter(const int* __restrict__ src, const int* __restrict__ dstA,
    int* __restrict__ cursor, int* __restrict__ csr_src, int E){
  int e = blockIdx.x * blockDim.x + threadIdx.x;
  if (e < E){
    int d = dstA[e];
    int pos = atomicAdd(&cursor[d], 1);
    csr_src[pos] = src[e];
  }
}

// ---- init (MFMA, swapped-D): merge = X@Wm + bm (bf16); outA = fp8(norm.*relu(X@Wp+bp+merge))
__global__ __launch_bounds__(512) void k_initM(const float* __restrict__ node,
    const u16* __restrict__ WT, const float* __restrict__ bpre,
    const float* __restrict__ bmrg, const float* __restrict__ norm,
    u16* __restrict__ merge, u8* __restrict__ outA, int n){
  __shared__ u16 Al[64 * 128];  // A tile, swizzled, 16KB
  int t = threadIdx.x;
  int w = t >> 6, l = t & 63;
  int n0 = blockIdx.x * 64;
  int cb = w * 32;
  int lk = (l >> 4) * 8;

  float nr4[4];
  #pragma unroll
  for (int fr = 0; fr < 4; ++fr){
    int row = n0 + fr * 16 + (l & 15);
    nr4[fr] = (row < n) ? norm[row] : 0.f;
  }
  float4 bPr[2], bMr[2];
  #pragma unroll
  for (int fcp = 0; fcp < 2; ++fcp){
    int j0 = cb + fcp * 16 + (l >> 4) * 4;
    bPr[fcp] = *(const float4*)(bpre + j0);
    bMr[fcp] = *(const float4*)(bmrg + j0);
  }

  {
    int row = t >> 3, c0 = (t & 7) * 16;
    const float* src = node + (size_t)(n0 + row) * ICNST + c0;
    bool ok = (n0 + row) < n;
    #pragma unroll
    for (int q = 0; q < 4; ++q){
      float4 v = ok ? *(const float4*)(src + q * 4) : float4{0.f, 0.f, 0.f, 0.f};
      int byte = (row * 256 + c0 * 2 + q * 8) ^ ((row & 7) << 4);
      uint2 pp; pp.x = pk2(v.x, v.y); pp.y = pk2(v.z, v.w);
      *(uint2*)((char*)Al + byte) = pp;
    }
  }
  __syncthreads();

  f32x4 acc[4][4] = {};
  #pragma unroll
  for (int ks = 0; ks < 4; ++ks){
    bf16x8 bf[4];
    #pragma unroll
    for (int fc = 0; fc < 4; ++fc){
      int j = (fc < 2) ? (cb + fc * 16 + (l & 15))
                       : (256 + cb + (fc - 2) * 16 + (l & 15));
      bf[fc] = *(const bf16x8*)(WT + (size_t)j * 128 + ks * 32 + lk);
    }
    bf16x8 af[4];
    #pragma unroll
    for (int fr = 0; fr < 4; ++fr){
      int row = fr * 16 + (l & 15);
      int byte = (row * 256 + ks * 64 + (l >> 4) * 16) ^ ((l & 7) << 4);
      af[fr] = *(const bf16x8*)((const char*)Al + byte);
    }
    #pragma unroll
    for (int fr = 0; fr < 4; ++fr)
      #pragma unroll
      for (int fc = 0; fc < 4; ++fc)
        acc[fr][fc] = __builtin_amdgcn_mfma_f32_16x16x32_bf16(bf[fc], af[fr], acc[fr][fc], 0, 0, 0);
  }

  #pragma unroll
  for (int fr = 0; fr < 4; ++fr){
    int row = n0 + fr * 16 + (l & 15);
    bool ok = row < n;
    float nr = nr4[fr];
    #pragma unroll
    for (int fcp = 0; fcp < 2; ++fcp){
      int j0 = cb + fcp * 16 + (l >> 4) * 4;
      f32x4 aP = acc[fr][fcp], aM = acc[fr][fcp + 2];
      float bPe[4] = {bPr[fcp].x, bPr[fcp].y, bPr[fcp].z, bPr[fcp].w};
      float bMe[4] = {bMr[fcp].x, bMr[fcp].y, bMr[fcp].z, bMr[fcp].w};
      ushort4 mgv;
      u16* mgp = (u16*)&mgv;
      float o4[4];
      #pragma unroll
      for (int r = 0; r < 4; ++r){
        float mg = aM[r] + bMe[r];
        float o  = aP[r] + bPe[r] + mg;
        o = (o > 0.f) ? o : 0.f;
        mgp[r] = f2bf(mg);
        o4[r] = nr * o;
      }
      if (ok){
        *(ushort4*)(merge + (size_t)row * C2 + j0) = mgv;
        *(unsigned int*)(outA + (size_t)row * C2 + j0) = pk4fp8(o4[0], o4[1], o4[2], o4[3]);
      }
    }
  }
}

// ---- FUSED prop + conv (MFMA, swapped-D), fp8 state ----
// PROP: quarter-wave (16 lanes x uint4 = one 256B row per quarter)
template<int FINAL>
__global__ __launch_bounds__(512) void k_pconv(const u8* __restrict__ src,
    const int* __restrict__ row_start, const int* __restrict__ csr,
    const float* __restrict__ norm,
    const u16* __restrict__ Wc, const float* __restrict__ bc,
    const u16* __restrict__ merge,
    u8* __restrict__ dstB, float* __restrict__ out, int n, int Etot){
  __shared__ u16 Al[64 * 256];  // bf16 A tile (prop result), swizzled, 32KB
  int t = threadIdx.x;
  int w = t >> 6, l = t & 63;
  int n0 = blockIdx.x * 64;
  int wh = w >> 2;
  int lk = (l >> 4) * 8;
  int q = l >> 4;               // quarter index 0..3
  int c16 = l & 15;             // lane-in-quarter: 16B (16 fp8 channels) per lane

  float nr4[4];
  #pragma unroll
  for (int fr = 0; fr < 4; ++fr){
    int row = n0 + fr * 16 + (l & 15);
    nr4[fr] = (row < n) ? norm[row] : 0.f;
  }
  float4 bCr[2];
  #pragma unroll
  for (int fc = 0; fc < 2; ++fc)
    bCr[fc] = *(const float4*)(bc + w * 32 + fc * 16 + (l >> 4) * 4);

  // ---- PROP phase: quarter-wave owns 2 rows in flight; uint4 row segments ----
  const u8* Ac = src + (size_t)c16 * 16;
  int rbase = w * 8 + q * 2;
  float acc16[2][16];
  int bb[2], ee[2];
  float ndk[2];
  #pragma unroll
  for (int k = 0; k < 2; ++k){
    int gw = n0 + rbase + k;
    bool ok = gw < n;
    bb[k] = ok ? row_start[gw] : 0;
    ee[k] = ok ? row_start[gw + 1] : 0;
    ndk[k] = ok ? norm[gw] : 0.f;
    #pragma unroll
    for (int m = 0; m < 16; ++m) acc16[k][m] = 0.f;
  }
  int Em1 = Etot - 1;
  bool more = (bb[0] < ee[0]) | (bb[1] < ee[1]);
  while (__any(more)){
    uint4 rr[2];
    float wk[2];
    #pragma unroll
    for (int k = 0; k < 2; ++k){
      bool v = bb[k] < ee[k];
      wk[k] = v ? 1.f : 0.f;
      int idx = (bb[k] < Em1) ? bb[k] : Em1;
      int s0 = csr[idx];
      rr[k] = *(const uint4*)(Ac + (size_t)s0 * C2);
      bb[k] += v ? 1 : 0;
    }
    #pragma unroll
    for (int k = 0; k < 2; ++k){
      f32x2 p;
      p = up2<false>(rr[k].x); acc16[k][ 0] = fmaf(wk[k], p.x, acc16[k][ 0]); acc16[k][ 1] = fmaf(wk[k], p.y, acc16[k][ 1]);
      p = up2<true >(rr[k].x); acc16[k][ 2] = fmaf(wk[k], p.x, acc16[k][ 2]); acc16[k][ 3] = fmaf(wk[k], p.y, acc16[k][ 3]);
      p = up2<false>(rr[k].y); acc16[k][ 4] = fmaf(wk[k], p.x, acc16[k][ 4]); acc16[k][ 5] = fmaf(wk[k], p.y, acc16[k][ 5]);
      p = up2<true >(rr[k].y); acc16[k][ 6] = fmaf(wk[k], p.x, acc16[k][ 6]); acc16[k][ 7] = fmaf(wk[k], p.y, acc16[k][ 7]);
      p = up2<false>(rr[k].z); acc16[k][ 8] = fmaf(wk[k], p.x, acc16[k][ 8]); acc16[k][ 9] = fmaf(wk[k], p.y, acc16[k][ 9]);
      p = up2<true >(rr[k].z); acc16[k][10] = fmaf(wk[k], p.x, acc16[k][10]); acc16[k][11] = fmaf(wk[k], p.y, acc16[k][11]);
      p = up2<false>(rr[k].w); acc16[k][12] = fmaf(wk[k], p.x, acc16[k][12]); acc16[k][13] = fmaf(wk[k], p.y, acc16[k][13]);
      p = up2<true >(rr[k].w); acc16[k][14] = fmaf(wk[k], p.x, acc16[k][14]); acc16[k][15] = fmaf(wk[k], p.y, acc16[k][15]);
    }
    more = (bb[0] < ee[0]) | (bb[1] < ee[1]);
  }
  // write 2 rows (16 bf16 channels per lane = 32B = 2x uint4) to swizzled LDS
  #pragma unroll
  for (int k = 0; k < 2; ++k){
    int rl = rbase + k;
    float nd = ndk[k];
    uint4 v0, v1;
    v0.x = pk2(nd * acc16[k][ 0], nd * acc16[k][ 1]);
    v0.y = pk2(nd * acc16[k][ 2], nd * acc16[k][ 3]);
    v0.z = pk2(nd * acc16[k][ 4], nd * acc16[k][ 5]);
    v0.w = pk2(nd * acc16[k][ 6], nd * acc16[k][ 7]);
    v1.x = pk2(nd * acc16[k][ 8], nd * acc16[k][ 9]);
    v1.y = pk2(nd * acc16[k][10], nd * acc16[k][11]);
    v1.z = pk2(nd * acc16[k][12], nd * acc16[k][13]);
    v1.w = pk2(nd * acc16[k][14], nd * acc16[k][15]);
    int base2 = rl * 512 + c16 * 32;
    int sw = (rl & 7) << 4;
    *(uint4*)((char*)Al + (base2 ^ sw)) = v0;
    *(uint4*)((char*)Al + ((base2 + 16) ^ sw)) = v1;
  }
  __syncthreads();

  // ---- CONV phase ----
  f32x4 acc[4][2] = {};
  #pragma unroll
  for (int ks = 0; ks < 4; ++ks){
    bf16x8 bf[2];
    #pragma unroll
    for (int fc = 0; fc < 2; ++fc){
      int rw = w * 32 + fc * 16 + (l & 15);
      bf[fc] = *(const bf16x8*)(Wc + (size_t)rw * 128 + ks * 32 + lk);
    }
    bf16x8 af[4];
    #pragma unroll
    for (int fr = 0; fr < 4; ++fr){
      int row = fr * 16 + (l & 15);
      int byte = (row * 512 + wh * 256 + ks * 64 + (l >> 4) * 16) ^ ((l & 7) << 4);
      af[fr] = *(const bf16x8*)((const char*)Al + byte);
    }
    #pragma unroll
    for (int fr = 0; fr < 4; ++fr)
      #pragma unroll
      for (int fc = 0; fc < 2; ++fc)
        acc[fr][fc] = __builtin_amdgcn_mfma_f32_16x16x32_bf16(bf[fc], af[fr], acc[fr][fc], 0, 0, 0);
  }

  // epilogue
  #pragma unroll
  for (int fr = 0; fr < 4; ++fr){
    int row = n0 + fr * 16 + (l & 15);
    bool ok = row < n;
    float nr = nr4[fr];
    #pragma unroll
    for (int fc = 0; fc < 2; ++fc){
      int j0 = w * 32 + fc * 16 + (l >> 4) * 4;
      ushort4 mg4 = ok ? *(const ushort4*)(merge + (size_t)row * C2 + j0)
                       : ushort4{0, 0, 0, 0};
      const u16* mge = (const u16*)&mg4;
      float bCe[4] = {bCr[fc].x, bCr[fc].y, bCr[fc].z, bCr[fc].w};
      float v[4];
      #pragma unroll
      for (int r = 0; r < 4; ++r){
        float o = acc[fr][fc][r] + bCe[r] + bf2f(mge[r]);
        v[r] = (o > 0.f) ? o : 0.f;
      }
      if (ok){
        if (!FINAL){
          *(unsigned int*)(dstB + (size_t)row * C2 + j0) =
              pk4fp8(nr * v[0], nr * v[1], nr * v[2], nr * v[3]);
        } else {
          float2 om;
          om.x = 0.5f * (v[0] + v[1]);
          om.y = 0.5f * (v[2] + v[3]);
          *(float2*)(out + (size_t)row * 128 + (j0 >> 1)) = om;
        }
      }
    }
  }
}

extern "C" void kernel_launch(void* const* d_in, const int* in_sizes, int n_in,
                              void* d_out, int out_size, void* d_ws, size_t ws_size,
                              hipStream_t stream){
  const float* node = (const float*)d_in[0];
  const int*   eidx = (const int*)d_in[1];
  const float* Wpre = (const float*)d_in[2];
  const float* bpre = (const float*)d_in[3];
  const float* Wmrg = (const float*)d_in[4];
  const float* bmrg = (const float*)d_in[5];
  const float* Wcv  = (const float*)d_in[6];
  const float* bcv  = (const float*)d_in[7];
  float* out = (float*)d_out;

  const int n = in_sizes[0] / ICNST;
  const int E = in_sizes[1] / 2;
  const int* srcp = eidx;
  const int* dstp = eidx + E;

  char* ws = (char*)d_ws;
  size_t off = 0;
  auto alloc = [&](size_t bytes) -> char* {
    char* p = ws + off;
    off += bytes;
    off = (off + 255) & ~(size_t)255;
    return p;
  };
  int*   deg       = (int*)  alloc((size_t)n * 4);
  float* norm      = (float*)alloc((size_t)n * 4);
  int*   row_start = (int*)  alloc((size_t)(n + 1) * 4);
  int*   cursor    = (int*)  alloc((size_t)n * 4);
  int*   csr       = (int*)  alloc((size_t)E * 4);
  u16*   merge     = (u16*)  alloc((size_t)n * C2 * 2);
  u8*    bufA      = (u8*)   alloc((size_t)n * C2);
  u8*    bufB      = (u8*)   alloc((size_t)n * C2);
  u16*   WT        = (u16*)  alloc((size_t)512 * 128 * 2);
  u16*   Wcbf      = (u16*)  alloc((size_t)2 * 128 * 128 * 2);
  int*   bsum      = (int*)  alloc((size_t)256 * 4);
  (void)ws_size; (void)n_in; (void)out_size;

  const int nb = (n + 255) / 256;

  k_zero<<<(n + 511) / 512, 512, 0, stream>>>(deg, n);
  k_pre<<<384 + (E + 255) / 256, 256, 0, stream>>>(dstp, deg, Wpre, Wmrg, Wcv, WT, Wcbf, E);
  k_scan1<<<nb, 256, 0, stream>>>(deg, bsum, n);
  k_scan2<<<1, 256, 0, stream>>>(bsum, nb);
  k_scan3<<<nb, 256, 0, stream>>>(deg, bsum, row_start, cursor, norm, n);
  k_scatter<<<(E + 255) / 256, 256, 0, stream>>>(srcp, dstp, cursor, csr, E);

  int gb64 = (n + 63) / 64;
  k_initM<<<gb64, 512, 0, stream>>>(node, WT, bpre, bmrg, norm, merge, bufA, n);

  // iteration 1: fused prop+conv, bufA(fp8) -> bufB(fp8)
  k_pconv<0><<<gb64, 512, 0, stream>>>(bufA, row_start, csr, norm, Wcbf, bcv, merge, bufB, nullptr, n, E);
  // iteration 2: fused prop+conv + final mean, bufB(fp8) -> out (f32)
  k_pconv<1><<<gb64, 512, 0, stream>>>(bufB, row_start, csr, norm, Wcbf, bcv, merge, nullptr, out, n, E);
}